// Round 2
// baseline (325.854 us; speedup 1.0000x reference)
//
#include <hip/hip_runtime.h>

// AttentionFusion: fused = sigmoid(x1.w - x2.w)*x1 + (1-sig)*x2, per row.
// N=16384 rows, D=2048 cols, fp32.
//
// v2b: wave-per-row, barrier-free (compile fix for nontemporal builtins).
//  - Each 64-lane wave owns one full row (32 floats = 8 float4 per lane per
//    input). No __syncthreads, no LDS: the row-dot reduce is a pure
//    __shfl_xor butterfly, so waves never wait on each other.
//  - 16 float4 loads per lane issued back-to-back (256 B in flight/lane)
//    vs 6 in v1 -> much deeper memory-level parallelism.
//  - fused output uses NONTEMPORAL stores via native ext_vector types
//    (__builtin_nontemporal_store rejects HIP_vector_type): the 128 MiB
//    output stream was evicting the 256 MiB x1+x2 working set from
//    Infinity Cache (FETCH showed 50% L3 hit).

#define NROWS 16384
#define DCOLS 2048
// 4 waves per 256-thread block, one row per wave.
#define NBLOCKS (NROWS / 4)

typedef float f32x4 __attribute__((ext_vector_type(4)));
typedef float f32x2 __attribute__((ext_vector_type(2)));

__global__ __launch_bounds__(256) void attn_fuse_kernel(
    const float* __restrict__ x1,
    const float* __restrict__ x2,
    const float* __restrict__ w,
    float* __restrict__ fused,
    float* __restrict__ alpha)
{
    const int lane = threadIdx.x & 63;
    const int row  = (blockIdx.x << 2) + (threadIdx.x >> 6);

    const f32x4* __restrict__ x1v = (const f32x4*)(x1 + (size_t)row * DCOLS);
    const f32x4* __restrict__ x2v = (const f32x4*)(x2 + (size_t)row * DCOLS);
    const f32x4* __restrict__ wv  = (const f32x4*)w;

    // 512 float4 per row, 64 lanes -> 8 per lane, stride-64 (coalesced:
    // each wave instruction touches a contiguous 1 KiB segment).
    f32x4 a[8], b[8], wr[8];
    #pragma unroll
    for (int i = 0; i < 8; ++i) a[i] = x1v[lane + (i << 6)];
    #pragma unroll
    for (int i = 0; i < 8; ++i) b[i] = x2v[lane + (i << 6)];
    #pragma unroll
    for (int i = 0; i < 8; ++i) wr[i] = wv[lane + (i << 6)];  // L1-hot, 8 KiB

    // Partial of dot(x1 - x2, w): only the score difference matters.
    float p = 0.0f;
    #pragma unroll
    for (int i = 0; i < 8; ++i) {
        p = fmaf(a[i].x - b[i].x, wr[i].x, p);
        p = fmaf(a[i].y - b[i].y, wr[i].y, p);
        p = fmaf(a[i].z - b[i].z, wr[i].z, p);
        p = fmaf(a[i].w - b[i].w, wr[i].w, p);
    }

    // Full-wave butterfly: every lane ends with the row sum. No LDS, no
    // barrier -> waves in a block proceed independently.
    #pragma unroll
    for (int off = 1; off < 64; off <<= 1)
        p += __shfl_xor(p, off, 64);

    const float a1g = 1.0f / (1.0f + expf(-p));  // alpha1 = sigmoid(s1 - s2)

    // fused = x2 + alpha1*(x1 - x2), straight from registers.
    f32x4* __restrict__ outv = (f32x4*)(fused + (size_t)row * DCOLS);
    #pragma unroll
    for (int i = 0; i < 8; ++i) {
        f32x4 f;
        f.x = fmaf(a1g, a[i].x - b[i].x, b[i].x);
        f.y = fmaf(a1g, a[i].y - b[i].y, b[i].y);
        f.z = fmaf(a1g, a[i].z - b[i].z, b[i].z);
        f.w = fmaf(a1g, a[i].w - b[i].w, b[i].w);
        // Nontemporal: don't let the output stream evict x1/x2 from L3.
        __builtin_nontemporal_store(f, outv + lane + (i << 6));
    }

    if (lane == 0) {
        f32x2 al;
        al.x = a1g;
        al.y = 1.0f - a1g;
        __builtin_nontemporal_store(al, (f32x2*)(alpha + (size_t)row * 2));
    }
}

extern "C" void kernel_launch(void* const* d_in, const int* in_sizes, int n_in,
                              void* d_out, int out_size, void* d_ws, size_t ws_size,
                              hipStream_t stream)
{
    const float* x1 = (const float*)d_in[0];
    const float* x2 = (const float*)d_in[1];
    const float* w  = (const float*)d_in[2];

    float* fused = (float*)d_out;                       // [N, D]
    float* alpha = fused + (size_t)NROWS * DCOLS;       // [N, 2]

    attn_fuse_kernel<<<NBLOCKS, 256, 0, stream>>>(x1, x2, w, fused, alpha);
}

// Round 3
// 311.287 us; speedup vs baseline: 1.0468x; 1.0468x over previous
//
#include <hip/hip_runtime.h>

// AttentionFusion: fused = sigmoid(x1.w - x2.w)*x1 + (1-sig)*x2, per row.
// N=16384 rows, D=2048 cols, fp32.
//
// v3: v1's block shape (256 thr, 2 float4/thread/input) + 8 rows per block,
// software-pipelined: row r+1's loads are issued before row r's reduce, so
// memory is in flight during the shuffle/LDS/barrier/store phases instead
// of bursting once per block.
//  - Double-buffered registers, full unroll -> all buffer indices static
//    (runtime-indexed ext_vector arrays would spill to scratch).
//  - Alternating LDS slots (wave_sum[r&1]) -> one __syncthreads per row,
//    no WAR hazard (two barriers separate reuse of a slot).
//  - Small live set (~16 float4) so the compiler keeps it in registers
//    instead of rematerializing loads (v2b's failure: VGPR=48 meant the
//    compiler reloaded x1/x2 after the reduce, serializing the store phase).

#define NROWS 16384
#define DCOLS 2048
#define RPB 8
#define NBLOCKS (NROWS / RPB)

typedef float f32x4 __attribute__((ext_vector_type(4)));

__global__ __launch_bounds__(256) void attn_fuse_kernel(
    const float* __restrict__ x1,
    const float* __restrict__ x2,
    const float* __restrict__ w,
    float* __restrict__ fused,
    float* __restrict__ alpha)
{
    const int t = threadIdx.x;
    const int wave = t >> 6;
    const int lane = t & 63;
    const size_t row0 = (size_t)blockIdx.x * RPB;

    const f32x4* __restrict__ wv = (const f32x4*)w;
    const f32x4 w0 = wv[t];         // w is 8 KiB, L1/L2-hot
    const f32x4 w1 = wv[t + 256];

    __shared__ float wave_sum[2][4];

    // Double-buffered row data: [buf] x {two float4 per input}.
    f32x4 a0[2], a1[2], b0[2], b1[2];

    {   // prologue: row 0 -> buffer 0
        const f32x4* __restrict__ x1v = (const f32x4*)(x1 + row0 * DCOLS);
        const f32x4* __restrict__ x2v = (const f32x4*)(x2 + row0 * DCOLS);
        a0[0] = x1v[t]; a1[0] = x1v[t + 256];
        b0[0] = x2v[t]; b1[0] = x2v[t + 256];
    }

    #pragma unroll
    for (int r = 0; r < RPB; ++r) {
        const int cur = r & 1;
        const int nxt = cur ^ 1;

        // Issue next row's loads NOW; first use is next iteration's dot,
        // so they are in flight across this row's reduce+barrier+store.
        if (r + 1 < RPB) {
            const f32x4* __restrict__ x1v =
                (const f32x4*)(x1 + (row0 + r + 1) * DCOLS);
            const f32x4* __restrict__ x2v =
                (const f32x4*)(x2 + (row0 + r + 1) * DCOLS);
            a0[nxt] = x1v[t]; a1[nxt] = x1v[t + 256];
            b0[nxt] = x2v[t]; b1[nxt] = x2v[t + 256];
        }

        // Partial of dot(x1 - x2, w) for the current row.
        float p = 0.0f;
        p = fmaf(a0[cur].x - b0[cur].x, w0.x, p);
        p = fmaf(a0[cur].y - b0[cur].y, w0.y, p);
        p = fmaf(a0[cur].z - b0[cur].z, w0.z, p);
        p = fmaf(a0[cur].w - b0[cur].w, w0.w, p);
        p = fmaf(a1[cur].x - b1[cur].x, w1.x, p);
        p = fmaf(a1[cur].y - b1[cur].y, w1.y, p);
        p = fmaf(a1[cur].z - b1[cur].z, w1.z, p);
        p = fmaf(a1[cur].w - b1[cur].w, w1.w, p);

        // Wave-64 reduce.
        #pragma unroll
        for (int off = 32; off > 0; off >>= 1)
            p += __shfl_down(p, off, 64);

        // Cross-wave reduce via alternating LDS slot; one barrier per row.
        if (lane == 0) wave_sum[cur][wave] = p;
        __syncthreads();
        const float d = wave_sum[cur][0] + wave_sum[cur][1]
                      + wave_sum[cur][2] + wave_sum[cur][3];

        const float g = 1.0f / (1.0f + expf(-d));  // alpha1

        // fused = x2 + alpha1*(x1 - x2), from registers.
        f32x4 f0, f1;
        f0.x = fmaf(g, a0[cur].x - b0[cur].x, b0[cur].x);
        f0.y = fmaf(g, a0[cur].y - b0[cur].y, b0[cur].y);
        f0.z = fmaf(g, a0[cur].z - b0[cur].z, b0[cur].z);
        f0.w = fmaf(g, a0[cur].w - b0[cur].w, b0[cur].w);
        f1.x = fmaf(g, a1[cur].x - b1[cur].x, b1[cur].x);
        f1.y = fmaf(g, a1[cur].y - b1[cur].y, b1[cur].y);
        f1.z = fmaf(g, a1[cur].z - b1[cur].z, b1[cur].z);
        f1.w = fmaf(g, a1[cur].w - b1[cur].w, b1[cur].w);

        f32x4* __restrict__ outv = (f32x4*)(fused + (row0 + r) * DCOLS);
        outv[t] = f0;
        outv[t + 256] = f1;

        if (t == 0) {
            alpha[(row0 + r) * 2]     = g;
            alpha[(row0 + r) * 2 + 1] = 1.0f - g;
        }
    }
}

extern "C" void kernel_launch(void* const* d_in, const int* in_sizes, int n_in,
                              void* d_out, int out_size, void* d_ws, size_t ws_size,
                              hipStream_t stream)
{
    const float* x1 = (const float*)d_in[0];
    const float* x2 = (const float*)d_in[1];
    const float* w  = (const float*)d_in[2];

    float* fused = (float*)d_out;                       // [N, D]
    float* alpha = fused + (size_t)NROWS * DCOLS;       // [N, 2]

    attn_fuse_kernel<<<NBLOCKS, 256, 0, stream>>>(x1, x2, w, fused, alpha);
}

// Round 4
// 305.284 us; speedup vs baseline: 1.0674x; 1.0197x over previous
//
#include <hip/hip_runtime.h>

// AttentionFusion: fused = sigmoid(x1.w - x2.w)*x1 + (1-sig)*x2, per row.
// N=16384 rows, D=2048 cols, fp32.
//
// v4: two CONCURRENT rows per 256-thread block (not pipelined — v3 showed
// hipcc sinks next-iteration loads below the barrier, VGPR=28).
//  - All 12 x-loads (2 rows x {x1,x2} x 2 float4) are pre-barrier uses, so
//    the compiler cannot sink them: one 192 B/thread burst, 2x v1's MLP.
//  - Two dot/shuffle chains interleave -> shuffle latency hidden.
//  - One __syncthreads serves both rows' reduces (half v1's barrier cost
//    per byte).
//  - Live set across the barrier = 2 rows x {diff,b} = 32 floats — only 2x
//    what the compiler demonstrably keeps live (v1/v3), so it should stay
//    in registers instead of being rematerialized (v2b's failure).

#define NROWS 16384
#define DCOLS 2048
#define RPB 2
#define NBLOCKS (NROWS / RPB)

typedef float f32x4 __attribute__((ext_vector_type(4)));

__global__ __launch_bounds__(256) void attn_fuse_kernel(
    const float* __restrict__ x1,
    const float* __restrict__ x2,
    const float* __restrict__ w,
    float* __restrict__ fused,
    float* __restrict__ alpha)
{
    const int t = threadIdx.x;
    const int wave = t >> 6;
    const int lane = t & 63;
    const size_t r0 = (size_t)blockIdx.x * RPB;

    const f32x4* __restrict__ x1a = (const f32x4*)(x1 + r0 * DCOLS);
    const f32x4* __restrict__ x2a = (const f32x4*)(x2 + r0 * DCOLS);
    const f32x4* __restrict__ x1b = (const f32x4*)(x1 + (r0 + 1) * DCOLS);
    const f32x4* __restrict__ x2b = (const f32x4*)(x2 + (r0 + 1) * DCOLS);

    // One burst: 12 float4 global loads, all needed before the barrier.
    f32x4 aA0 = x1a[t], aA1 = x1a[t + 256];
    f32x4 bA0 = x2a[t], bA1 = x2a[t + 256];
    f32x4 aB0 = x1b[t], aB1 = x1b[t + 256];
    f32x4 bB0 = x2b[t], bB1 = x2b[t + 256];

    const f32x4* __restrict__ wv = (const f32x4*)w;
    const f32x4 w0 = wv[t];        // 8 KiB, L1-hot after first block
    const f32x4 w1 = wv[t + 256];

    // Keep diff and b live; drop a (matches the allocation the compiler
    // chose in v1: fuse = b + g*diff).
    const f32x4 dA0 = aA0 - bA0, dA1 = aA1 - bA1;
    const f32x4 dB0 = aB0 - bB0, dB1 = aB1 - bB1;

    float pA = 0.0f, pB = 0.0f;
    pA = fmaf(dA0.x, w0.x, pA); pA = fmaf(dA0.y, w0.y, pA);
    pA = fmaf(dA0.z, w0.z, pA); pA = fmaf(dA0.w, w0.w, pA);
    pA = fmaf(dA1.x, w1.x, pA); pA = fmaf(dA1.y, w1.y, pA);
    pA = fmaf(dA1.z, w1.z, pA); pA = fmaf(dA1.w, w1.w, pA);
    pB = fmaf(dB0.x, w0.x, pB); pB = fmaf(dB0.y, w0.y, pB);
    pB = fmaf(dB0.z, w0.z, pB); pB = fmaf(dB0.w, w0.w, pB);
    pB = fmaf(dB1.x, w1.x, pB); pB = fmaf(dB1.y, w1.y, pB);
    pB = fmaf(dB1.z, w1.z, pB); pB = fmaf(dB1.w, w1.w, pB);

    // Two interleaved wave-64 reduces (independent -> latency overlaps).
    #pragma unroll
    for (int off = 32; off > 0; off >>= 1) {
        pA += __shfl_down(pA, off, 64);
        pB += __shfl_down(pB, off, 64);
    }

    __shared__ float wsum[2][4];
    if (lane == 0) { wsum[0][wave] = pA; wsum[1][wave] = pB; }
    __syncthreads();
    const float sA = wsum[0][0] + wsum[0][1] + wsum[0][2] + wsum[0][3];
    const float sB = wsum[1][0] + wsum[1][1] + wsum[1][2] + wsum[1][3];

    const float gA = 1.0f / (1.0f + expf(-sA));
    const float gB = 1.0f / (1.0f + expf(-sB));

    // fused = b + g*diff, straight from registers.
    f32x4* __restrict__ outA = (f32x4*)(fused + r0 * DCOLS);
    f32x4* __restrict__ outB = (f32x4*)(fused + (r0 + 1) * DCOLS);
    outA[t]       = bA0 + gA * dA0;
    outA[t + 256] = bA1 + gA * dA1;
    outB[t]       = bB0 + gB * dB0;
    outB[t + 256] = bB1 + gB * dB1;

    if (t == 0) {
        alpha[r0 * 2]     = gA;
        alpha[r0 * 2 + 1] = 1.0f - gA;
        alpha[r0 * 2 + 2] = gB;
        alpha[r0 * 2 + 3] = 1.0f - gB;
    }
}

extern "C" void kernel_launch(void* const* d_in, const int* in_sizes, int n_in,
                              void* d_out, int out_size, void* d_ws, size_t ws_size,
                              hipStream_t stream)
{
    const float* x1 = (const float*)d_in[0];
    const float* x2 = (const float*)d_in[1];
    const float* w  = (const float*)d_in[2];

    float* fused = (float*)d_out;                       // [N, D]
    float* alpha = fused + (size_t)NROWS * DCOLS;       // [N, 2]

    attn_fuse_kernel<<<NBLOCKS, 256, 0, stream>>>(x1, x2, w, fused, alpha);
}

// Round 5
// 305.137 us; speedup vs baseline: 1.0679x; 1.0005x over previous
//
#include <hip/hip_runtime.h>

// AttentionFusion: fused = sigmoid(x1.w - x2.w)*x1 + (1-sig)*x2, per row.
// N=16384 rows, D=2048 cols, fp32.
//
// v5: global_load_lds staging (HBM -> LDS direct, no VGPR destinations).
// Rounds 1-4 showed hipcc ALWAYS rematerializes post-barrier row reads from
// L2 (VGPR pinned at 20-32 in every variant) and sinks register prefetches
// below barriers. So: stage each row pair into LDS asynchronously; the dot
// reads LDS, and the fuse re-reads the SAME LDS (69 TB/s) instead of
// round-tripping to L2. VGPR ~30 + 16.4 KB LDS -> 8 blocks/CU = 32 waves
// (occupancy ~100% vs 70%), more decorrelated load bursts per CU.
//  - LDS dest of global_load_lds is wave-uniform base + lane*16 (HW rule);
//    global src is per-lane. Layout is linear, matching lane order.
//  - __syncthreads() after the stage gives exactly the vmcnt(0)+barrier
//    drain semantics the staged data needs.

#define NROWS 16384
#define DCOLS 2048

typedef float f32x4 __attribute__((ext_vector_type(4)));

__device__ __forceinline__ void stage16(const void* g, void* l)
{
    __builtin_amdgcn_global_load_lds(
        (const __attribute__((address_space(1))) void*)g,
        (__attribute__((address_space(3))) void*)l, 16, 0, 0);
}

__global__ __launch_bounds__(256) void attn_fuse_kernel(
    const float* __restrict__ x1,
    const float* __restrict__ x2,
    const float* __restrict__ w,
    float* __restrict__ fused,
    float* __restrict__ alpha)
{
    __shared__ float x1L[DCOLS];   // 8 KiB
    __shared__ float x2L[DCOLS];   // 8 KiB
    __shared__ float wsum[4];

    const int t = threadIdx.x;
    const int wave = t >> 6;
    const int lane = t & 63;
    const size_t row = blockIdx.x;

    // Async stage: each wave stages 2 KiB of x1 and 2 KiB of x2
    // (4 x 1 KiB wave-level global_load_lds, width 16 B).
    {
        const char* g1 = (const char*)(x1 + row * DCOLS) + wave * 2048 + lane * 16;
        const char* g2 = (const char*)(x2 + row * DCOLS) + wave * 2048 + lane * 16;
        char* l1 = (char*)x1L + wave * 2048;   // wave-uniform LDS base
        char* l2 = (char*)x2L + wave * 2048;
        stage16(g1,        l1);
        stage16(g1 + 1024, l1 + 1024);
        stage16(g2,        l2);
        stage16(g2 + 1024, l2 + 1024);
    }

    // w is 8 KiB, L1/L2-hot after the first blocks: plain vector loads.
    const f32x4* __restrict__ wv = (const f32x4*)w;
    const f32x4 w0 = wv[t];
    const f32x4 w1 = wv[t + 256];

    __syncthreads();   // vmcnt(0) drain + barrier: staged row visible

    // Dot phase: read row slices from LDS (contiguous lane*16B -> no
    // meaningful bank conflicts for b128 reads).
    const f32x4 a0 = ((const f32x4*)x1L)[t];
    const f32x4 a1 = ((const f32x4*)x1L)[t + 256];
    const f32x4 b0 = ((const f32x4*)x2L)[t];
    const f32x4 b1 = ((const f32x4*)x2L)[t + 256];

    float p = 0.0f;
    p = fmaf(a0.x - b0.x, w0.x, p);
    p = fmaf(a0.y - b0.y, w0.y, p);
    p = fmaf(a0.z - b0.z, w0.z, p);
    p = fmaf(a0.w - b0.w, w0.w, p);
    p = fmaf(a1.x - b1.x, w1.x, p);
    p = fmaf(a1.y - b1.y, w1.y, p);
    p = fmaf(a1.z - b1.z, w1.z, p);
    p = fmaf(a1.w - b1.w, w1.w, p);

    // Wave-64 reduce.
    #pragma unroll
    for (int off = 32; off > 0; off >>= 1)
        p += __shfl_down(p, off, 64);

    if (lane == 0) wsum[wave] = p;
    __syncthreads();
    const float d = wsum[0] + wsum[1] + wsum[2] + wsum[3];

    const float g = 1.0f / (1.0f + expf(-d));  // alpha1 = sigmoid(s1 - s2)

    // Fuse phase: a,b are either still in registers or re-read from hot
    // LDS -- never a trip to L2/global.
    f32x4 f0, f1;
    f0.x = fmaf(g, a0.x - b0.x, b0.x);
    f0.y = fmaf(g, a0.y - b0.y, b0.y);
    f0.z = fmaf(g, a0.z - b0.z, b0.z);
    f0.w = fmaf(g, a0.w - b0.w, b0.w);
    f1.x = fmaf(g, a1.x - b1.x, b1.x);
    f1.y = fmaf(g, a1.y - b1.y, b1.y);
    f1.z = fmaf(g, a1.z - b1.z, b1.z);
    f1.w = fmaf(g, a1.w - b1.w, b1.w);

    f32x4* __restrict__ outv = (f32x4*)(fused + row * DCOLS);
    outv[t] = f0;
    outv[t + 256] = f1;

    if (t == 0) {
        alpha[row * 2]     = g;
        alpha[row * 2 + 1] = 1.0f - g;
    }
}

extern "C" void kernel_launch(void* const* d_in, const int* in_sizes, int n_in,
                              void* d_out, int out_size, void* d_ws, size_t ws_size,
                              hipStream_t stream)
{
    const float* x1 = (const float*)d_in[0];
    const float* x2 = (const float*)d_in[1];
    const float* w  = (const float*)d_in[2];

    float* fused = (float*)d_out;                       // [N, D]
    float* alpha = fused + (size_t)NROWS * DCOLS;       // [N, 2]

    attn_fuse_kernel<<<NROWS, 256, 0, stream>>>(x1, x2, w, fused, alpha);
}